// Round 2
// baseline (118.582 us; speedup 1.0000x reference)
//
#include <hip/hip_runtime.h>

// Chamfer loss between subsampled point clouds.
// srcA: (64000,2) fp32 -> A = 8000 pts  (fp32 linspace trunc, matches jnp)
// srcB: (80000,2) fp32 -> B = 10000 pts
// out  = 0.5 * ( mean_i min_j |A_i - B_j| + mean_j min_i |A_i - B_j| )
//
// Expanded-form inner loop: for fixed row p,
//   argmin_j |p-q_j|^2 == argmax_j (2 p.q_j - |q_j|^2)
// Columns staged in LDS as float4 (2qx, 2qy, -|q|^2, 0) -> pair op is
//   M = fmax(M, fma(px,tqx, fma(py,tqy, negc)))   = 3 VALU ops/pair (vs 5).
// |p|^2 added back at the chunk store, so ws keeps "partial min of squared
// distance" semantics (sqrt is monotone; applied in the reduce).
//
// RPT=8 rows/thread so one b128 LDS broadcast feeds 24 VALU ops:
//   DS  : 16 B / 8 pairs = 2 B/pair  -> ~5-6 us floor (per-CU DS pipe)
//   VALU: 3 ops/pair                 -> ~6.1 us floor
// CHUNK=64 keeps the grid at 1253 blocks (~4.9/CU, 2% tail slack).
// LDS reads are same-address across the wave (broadcast, conflict-free).
//
// Two dispatches:
//  1) chamfer_partial: flat grid covering BOTH directions; partial max of
//     f' = 2p.q - |q|^2 per (row, chunk); store pp - M (= partial min d^2).
//     No atomics, no ws init needed. Block 0 zeroes d_out for the reduce.
//  2) reduce_out: min over chunks per row, clamp at 0 (expanded form can
//     round to -1e-7), sqrt, scaled sum, per-block atomicAdd into d_out.

#define SRC_A 64000
#define SRC_B 80000
#define NA 8000
#define NB 10000

#define BLOCK 256
#define CHUNK 64           // columns staged in LDS per block
#define RPT 8              // rows per thread
#define RPB (BLOCK * RPT)  // 2048 rows per block

#define NB1X 4    // ceil(8000/2048)   row-groups, pass 1
#define NB1Y 157  // ceil(10000/64)    col-chunks, pass 1
#define NB2X 5    // ceil(10000/2048)  row-groups, pass 2
#define NB2Y 125  // 8000/64           col-chunks, pass 2
#define NBLK1 (NB1X * NB1Y)           // 628
#define NBLK2 (NB2X * NB2Y)           // 625

#define P1_STRIDE (NB1X * RPB)        // 8192 (padded row count, pass 1)
#define P2_STRIDE (NB2X * RPB)        // 10240
// ws layout: P1 float[NB1Y * P1_STRIDE] @ 0 (5,144,576 B);
//            P2 float[NB2Y * P2_STRIDE] @ P2_OFF (5,120,000 B)
#define P2_OFF (NB1Y * P1_STRIDE * 4)

__global__ __launch_bounds__(BLOCK) void chamfer_partial(
        const float2* __restrict__ srcA, const float2* __restrict__ srcB,
        float* __restrict__ ws, float* __restrict__ out) {
    if (blockIdx.x == 0 && threadIdx.x == 0) *out = 0.0f;  // init for reduce's atomicAdd

    const bool pass1 = (int)blockIdx.x < NBLK1;
    const float2* srcRows; const float2* srcCols;
    float rowDelta, colDelta;
    int rowSrcMax, colSrcMax, nrows, ncols, bx, by, pstride;
    float* P;
    if (pass1) {
        int f = (int)blockIdx.x;
        bx = f % NB1X; by = f / NB1X;
        srcRows = srcA; rowDelta = (float)(SRC_A - 1) / (float)(NA - 1);
        rowSrcMax = SRC_A - 1; nrows = NA;
        srcCols = srcB; colDelta = (float)(SRC_B - 1) / (float)(NB - 1);
        colSrcMax = SRC_B - 1; ncols = NB;
        P = ws; pstride = P1_STRIDE;
    } else {
        int f = (int)blockIdx.x - NBLK1;
        bx = f % NB2X; by = f / NB2X;
        srcRows = srcB; rowDelta = (float)(SRC_B - 1) / (float)(NB - 1);
        rowSrcMax = SRC_B - 1; nrows = NB;
        srcCols = srcA; colDelta = (float)(SRC_A - 1) / (float)(NA - 1);
        colSrcMax = SRC_A - 1; ncols = NA;
        P = ws + (P2_OFF / 4); pstride = P2_STRIDE;
    }

    // stage columns as (2qx, 2qy, -|q|^2, 0)
    __shared__ __align__(16) float4 sc[CHUNK];
    int c0 = by * CHUNK;
    int cn = ncols - c0; if (cn > CHUNK) cn = CHUNK;
    int j = (int)threadIdx.x;
    if (j < cn) {
        int cidx = (int)((float)(c0 + j) * colDelta);
        if (cidx > colSrcMax) cidx = colSrcMax;
        float2 q = srcCols[cidx];
        sc[j] = make_float4(q.x + q.x, q.y + q.y, -fmaf(q.x, q.x, q.y * q.y), 0.0f);
    }
    __syncthreads();

    // 8 rows per thread: r_i = bx*2048 + i*256 + tid  (coalesced stores)
    float2 p[RPT];
    float  pp[RPT];   // |p|^2 per row
    float  M[RPT];    // running max of f' = 2p.q - |q|^2
    int r0 = bx * RPB + (int)threadIdx.x;
#pragma unroll
    for (int i = 0; i < RPT; ++i) {
        int r = r0 + i * BLOCK;
        int l = r < nrows ? r : nrows - 1;               // clamp for load; guard store
        int ridx = (int)((float)l * rowDelta);
        if (ridx > rowSrcMax) ridx = rowSrcMax;
        p[i] = srcRows[ridx];
        pp[i] = fmaf(p[i].x, p[i].x, p[i].y * p[i].y);
        M[i] = -__builtin_inff();
    }

    if (cn == CHUNK) {
        // hot path (281 of 282 chunks): compile-time trip count
#pragma unroll 4
        for (int k = 0; k < CHUNK; ++k) {
            float4 q = sc[k];  // broadcast across the wave: conflict-free
#pragma unroll
            for (int i = 0; i < RPT; ++i) {
                M[i] = fmaxf(M[i], fmaf(p[i].x, q.x, fmaf(p[i].y, q.y, q.z)));
            }
        }
    } else {
        for (int k = 0; k < cn; ++k) {
            float4 q = sc[k];
#pragma unroll
            for (int i = 0; i < RPT; ++i) {
                M[i] = fmaxf(M[i], fmaf(p[i].x, q.x, fmaf(p[i].y, q.y, q.z)));
            }
        }
    }

#pragma unroll
    for (int i = 0; i < RPT; ++i) {
        int r = r0 + i * BLOCK;
        if (r < nrows) P[by * pstride + r] = pp[i] - M[i];  // partial min of d^2
    }
}

__global__ __launch_bounds__(BLOCK) void reduce_out(const float* __restrict__ ws,
                                                    float* __restrict__ out) {
    const float* P1 = ws;
    const float* P2 = ws + (P2_OFF / 4);
    float s = 0.0f;
    for (int t = (int)(blockIdx.x * BLOCK + threadIdx.x); t < NA + NB;
         t += (int)(gridDim.x * BLOCK)) {
        float mn = __builtin_inff();
        if (t < NA) {
#pragma unroll 8
            for (int c = 0; c < NB1Y; ++c) mn = fminf(mn, P1[c * P1_STRIDE + t]);
            mn = fmaxf(mn, 0.0f);  // expanded form can round slightly negative
            s += sqrtf(mn) * (0.5f / (float)NA);
        } else {
            int r = t - NA;
#pragma unroll 8
            for (int c = 0; c < NB2Y; ++c) mn = fminf(mn, P2[c * P2_STRIDE + r]);
            mn = fmaxf(mn, 0.0f);
            s += sqrtf(mn) * (0.5f / (float)NB);
        }
    }
    // wave shuffle reduce, then LDS across the 4 waves, then one atomicAdd
    for (int off = 32; off > 0; off >>= 1) s += __shfl_down(s, off, 64);
    __shared__ float red[4];
    int wave = (int)threadIdx.x >> 6;
    if ((threadIdx.x & 63) == 0) red[wave] = s;
    __syncthreads();
    if (threadIdx.x == 0) {
        float t = red[0] + red[1] + red[2] + red[3];
        atomicAdd(out, t);
    }
}

extern "C" void kernel_launch(void* const* d_in, const int* in_sizes, int n_in,
                              void* d_out, int out_size, void* d_ws, size_t ws_size,
                              hipStream_t stream) {
    (void)in_sizes; (void)n_in; (void)out_size; (void)ws_size;
    const float2* srcA = (const float2*)d_in[0];  // img_render_points (1000*64*2)
    const float2* srcB = (const float2*)d_in[1];  // ref point cloud (80000*2)
    float* ws = (float*)d_ws;
    float* out = (float*)d_out;

    chamfer_partial<<<NBLK1 + NBLK2, BLOCK, 0, stream>>>(srcA, srcB, ws, out);
    reduce_out<<<64, BLOCK, 0, stream>>>(ws, out);
}

// Round 4
// 80.127 us; speedup vs baseline: 1.4799x; 1.4799x over previous
//
#include <hip/hip_runtime.h>

// Chamfer loss between subsampled point clouds.
// srcA: (64000,2) fp32 -> A = 8000 pts  (fp32 linspace trunc, matches jnp)
// srcB: (80000,2) fp32 -> B = 10000 pts
// out  = 0.5 * ( mean_i min_j |A_i - B_j| + mean_j min_i |A_i - B_j| )
//
// Expanded-form inner loop: for fixed row p,
//   argmin_j |p-q_j|^2 == argmax_j (2 p.q_j - |q_j|^2)
// Columns staged in LDS as float4 (2qx, 2qy, -|q|^2, 0) -> pair op is
//   M = fmax(M, fma(px,tqx, fma(py,tqy, negc)))   = 3 VALU ops/pair.
// |p|^2 added back at the chunk store, so ws keeps "partial min of squared
// distance" semantics (sqrt is monotone; applied in the reduce).
//
// RPT=8 rows/thread: one b128 LDS broadcast feeds 24 VALU ops
//   DS  : 2 B/pair  (~5 us floor)    VALU: 3 ops/pair (~6 us floor)
// CHUNK=64 -> 1253 blocks (~4.9/CU, balanced). LDS reads broadcast.
//
// reduce_out (rewritten after round-2 latency disaster: 64 blocks walking
// 157-deep strided chains = 50 us, 1.4% occupancy):
//   one block per 64 rows (282 blocks), 256 thr = 64 rows x 4 chunk-slices.
//   Coalesced 256B per chunk-step, ~8 loads in flight, LDS 4x64 cross-slice
//   min, wave-0 sqrt+scale+shuffle-sum, one atomicAdd per block.
//
// (Round 3 was an infra failure — container died twice; source re-audited,
//  no defect found, resubmitting the same experiment.)

#define SRC_A 64000
#define SRC_B 80000
#define NA 8000
#define NB 10000

#define BLOCK 256
#define CHUNK 64           // columns staged in LDS per block
#define RPT 8              // rows per thread
#define RPB (BLOCK * RPT)  // 2048 rows per block

#define NB1X 4    // ceil(8000/2048)   row-groups, pass 1
#define NB1Y 157  // ceil(10000/64)    col-chunks, pass 1
#define NB2X 5    // ceil(10000/2048)  row-groups, pass 2
#define NB2Y 125  // 8000/64           col-chunks, pass 2
#define NBLK1 (NB1X * NB1Y)           // 628
#define NBLK2 (NB2X * NB2Y)           // 625

#define P1_STRIDE (NB1X * RPB)        // 8192 (padded row count, pass 1)
#define P2_STRIDE (NB2X * RPB)        // 10240
// ws layout: P1 float[NB1Y * P1_STRIDE] @ 0;  P2 float[NB2Y * P2_STRIDE] @ P2_OFF
#define P2_OFF (NB1Y * P1_STRIDE * 4)

__global__ __launch_bounds__(BLOCK) void chamfer_partial(
        const float2* __restrict__ srcA, const float2* __restrict__ srcB,
        float* __restrict__ ws, float* __restrict__ out) {
    if (blockIdx.x == 0 && threadIdx.x == 0) *out = 0.0f;  // init for reduce's atomicAdd

    const bool pass1 = (int)blockIdx.x < NBLK1;
    const float2* srcRows; const float2* srcCols;
    float rowDelta, colDelta;
    int rowSrcMax, colSrcMax, nrows, ncols, bx, by, pstride;
    float* P;
    if (pass1) {
        int f = (int)blockIdx.x;
        bx = f % NB1X; by = f / NB1X;
        srcRows = srcA; rowDelta = (float)(SRC_A - 1) / (float)(NA - 1);
        rowSrcMax = SRC_A - 1; nrows = NA;
        srcCols = srcB; colDelta = (float)(SRC_B - 1) / (float)(NB - 1);
        colSrcMax = SRC_B - 1; ncols = NB;
        P = ws; pstride = P1_STRIDE;
    } else {
        int f = (int)blockIdx.x - NBLK1;
        bx = f % NB2X; by = f / NB2X;
        srcRows = srcB; rowDelta = (float)(SRC_B - 1) / (float)(NB - 1);
        rowSrcMax = SRC_B - 1; nrows = NB;
        srcCols = srcA; colDelta = (float)(SRC_A - 1) / (float)(NA - 1);
        colSrcMax = SRC_A - 1; ncols = NA;
        P = ws + (P2_OFF / 4); pstride = P2_STRIDE;
    }

    // stage columns as (2qx, 2qy, -|q|^2, 0)
    __shared__ __align__(16) float4 sc[CHUNK];
    int c0 = by * CHUNK;
    int cn = ncols - c0; if (cn > CHUNK) cn = CHUNK;
    int j = (int)threadIdx.x;
    if (j < cn) {
        int cidx = (int)((float)(c0 + j) * colDelta);
        if (cidx > colSrcMax) cidx = colSrcMax;
        float2 q = srcCols[cidx];
        sc[j] = make_float4(q.x + q.x, q.y + q.y, -fmaf(q.x, q.x, q.y * q.y), 0.0f);
    }
    __syncthreads();

    // 8 rows per thread: r_i = bx*2048 + i*256 + tid  (coalesced stores)
    float2 p[RPT];
    float  pp[RPT];   // |p|^2 per row
    float  M[RPT];    // running max of f' = 2p.q - |q|^2
    int r0 = bx * RPB + (int)threadIdx.x;
#pragma unroll
    for (int i = 0; i < RPT; ++i) {
        int r = r0 + i * BLOCK;
        int l = r < nrows ? r : nrows - 1;               // clamp for load; guard store
        int ridx = (int)((float)l * rowDelta);
        if (ridx > rowSrcMax) ridx = rowSrcMax;
        p[i] = srcRows[ridx];
        pp[i] = fmaf(p[i].x, p[i].x, p[i].y * p[i].y);
        M[i] = -__builtin_inff();
    }

    if (cn == CHUNK) {
        // hot path (281 of 282 chunks): compile-time trip count
#pragma unroll 4
        for (int k = 0; k < CHUNK; ++k) {
            float4 q = sc[k];  // broadcast across the wave: conflict-free
#pragma unroll
            for (int i = 0; i < RPT; ++i) {
                M[i] = fmaxf(M[i], fmaf(p[i].x, q.x, fmaf(p[i].y, q.y, q.z)));
            }
        }
    } else {
        for (int k = 0; k < cn; ++k) {
            float4 q = sc[k];
#pragma unroll
            for (int i = 0; i < RPT; ++i) {
                M[i] = fmaxf(M[i], fmaf(p[i].x, q.x, fmaf(p[i].y, q.y, q.z)));
            }
        }
    }

#pragma unroll
    for (int i = 0; i < RPT; ++i) {
        int r = r0 + i * BLOCK;
        if (r < nrows) P[by * pstride + r] = pp[i] - M[i];  // partial min of d^2
    }
}

// ---- reduce: 64 rows/block x 4 chunk-slices, coalesced, then LDS+shuffle ----
#define RB_ROWS 64
#define RB1 125   // 8000/64 (exact)
#define RB2 157   // ceil(10000/64)

__global__ __launch_bounds__(BLOCK) void reduce_out(const float* __restrict__ ws,
                                                    float* __restrict__ out) {
    int t  = (int)threadIdx.x;
    int rl = t & 63;        // row within block
    int sl = t >> 6;        // chunk-slice 0..3
    const bool p1 = (int)blockIdx.x < RB1;
    const float* P; int nrows, nch, pstr, rbase; float scale;
    if (p1) {
        P = ws;               nrows = NA; nch = NB1Y; pstr = P1_STRIDE;
        rbase = (int)blockIdx.x * RB_ROWS;            scale = 0.5f / (float)NA;
    } else {
        P = ws + (P2_OFF / 4); nrows = NB; nch = NB2Y; pstr = P2_STRIDE;
        rbase = ((int)blockIdx.x - RB1) * RB_ROWS;    scale = 0.5f / (float)NB;
    }
    int r = rbase + rl;                         // always < pstr (padded), guarded at use
    int per = (nch + 3) >> 2;
    int cb = sl * per;
    int ce = cb + per; if (ce > nch) ce = nch;

    float mn = __builtin_inff();
#pragma unroll 8
    for (int c = cb; c < ce; ++c) mn = fminf(mn, P[c * pstr + r]);

    __shared__ float red[4][RB_ROWS];
    red[sl][rl] = mn;
    __syncthreads();

    if (t < 64) {
        float m = fminf(fminf(red[0][rl], red[1][rl]),
                        fminf(red[2][rl], red[3][rl]));
        m = fmaxf(m, 0.0f);  // expanded form can round slightly negative
        float v = (r < nrows) ? sqrtf(m) * scale : 0.0f;
        for (int off = 32; off > 0; off >>= 1) v += __shfl_down(v, off, 64);
        if (rl == 0) atomicAdd(out, v);
    }
}

extern "C" void kernel_launch(void* const* d_in, const int* in_sizes, int n_in,
                              void* d_out, int out_size, void* d_ws, size_t ws_size,
                              hipStream_t stream) {
    (void)in_sizes; (void)n_in; (void)out_size; (void)ws_size;
    const float2* srcA = (const float2*)d_in[0];  // img_render_points (1000*64*2)
    const float2* srcB = (const float2*)d_in[1];  // ref point cloud (80000*2)
    float* ws = (float*)d_ws;
    float* out = (float*)d_out;

    chamfer_partial<<<NBLK1 + NBLK2, BLOCK, 0, stream>>>(srcA, srcB, ws, out);
    reduce_out<<<RB1 + RB2, BLOCK, 0, stream>>>(ws, out);
}